// Round 13
// baseline (434.721 us; speedup 1.0000x reference)
//
#include <hip/hip_runtime.h>
#include <cstdint>
#include <cstddef>

// ---------------------------------------------------------------------------
// 2-layer GCN, bf16 intermediates. R12/R13:
//  - init_kernel replaced by hipMemsetAsync(packed|counter = 0); self-loop
//    (+1.0 deg) folded into scan's dinv computation analytically
//  - scan2 merged into scan1 via last-block arrival (fence + device atomic)
//  - aggs: 8-deep unroll (2 nodes/wave x 8 rows in flight)
//  - gemms: bf16 MFMA 16x16x32 (gemm1 split-A hi+lo), from R10/R11
//  - CSR build: 1 returning u64 atomic/edge (count<<48 | fixed-point deg)
// ---------------------------------------------------------------------------

typedef unsigned long long u64;
typedef unsigned int u32;
typedef unsigned short u16;
typedef __attribute__((ext_vector_type(8))) short bf16x8;
typedef __attribute__((ext_vector_type(4))) float f32x4;

__device__ __forceinline__ float bflo(u32 u) { return __uint_as_float(u << 16); }
__device__ __forceinline__ float bfhi(u32 u) { return __uint_as_float(u & 0xffff0000u); }
__device__ __forceinline__ u32 f2bf(float f) {  // round-to-nearest-even
  u32 u = __float_as_uint(f);
  return (u + 0x7fffu + ((u >> 16) & 1u)) >> 16;
}
__device__ __forceinline__ u32 pack2bf(float lo, float hi) {
  return f2bf(lo) | (f2bf(hi) << 16);
}

__global__ void degrank_kernel(const int* __restrict__ dst, const float* __restrict__ w,
                               u64* packed, u16* __restrict__ rank, int E) {
  int e = blockIdx.x * 256 + threadIdx.x;
  if (e < E) {
    int d = dst[e];
    u64 add = (1ull << 48) | (u64)(w[e] * 4294967296.0f);
    u64 old = atomicAdd(&packed[d], add);
    rank[e] = (u16)(old >> 48);
  }
}

// ---- gemm1 (MFMA): h1[M,128](bf16) = x[M,128](fp32, split-A) @ W1[128,128] ----
__global__ __launch_bounds__(256) void gemm1_kernel(const float* __restrict__ x,
                                                    const float* __restrict__ W1,
                                                    u16* __restrict__ h1, int M) {
  __shared__ u16 Wt[128][136];  // [col][k], +8 pad; bf16
  const int tid = threadIdx.x;
  for (int i = tid; i < 128 * 128; i += 256) {
    int c = i >> 7, k = i & 127;
    Wt[c][k] = (u16)f2bf(W1[(size_t)k * 128 + c]);
  }
  __syncthreads();

  const int wv = tid >> 6;
  const int l = tid & 63;
  const int c16 = l & 15;
  const int kg = l >> 4;
  const int arow = blockIdx.x * 64 + wv * 16 + c16;
  const bool rok = arow < M;

  bf16x8 ahi[4], alo[4];
  #pragma unroll
  for (int kk = 0; kk < 4; ++kk) {
    float v[8];
    if (rok) {
      float4 p0 = *reinterpret_cast<const float4*>(x + (size_t)arow * 128 + kk * 32 + kg * 8);
      float4 p1 = *reinterpret_cast<const float4*>(x + (size_t)arow * 128 + kk * 32 + kg * 8 + 4);
      v[0] = p0.x; v[1] = p0.y; v[2] = p0.z; v[3] = p0.w;
      v[4] = p1.x; v[5] = p1.y; v[6] = p1.z; v[7] = p1.w;
    } else {
      #pragma unroll
      for (int j = 0; j < 8; ++j) v[j] = 0.f;
    }
    #pragma unroll
    for (int j = 0; j < 8; ++j) {
      u32 hb = f2bf(v[j]);
      float hf = __uint_as_float(hb << 16);
      u32 lb = f2bf(v[j] - hf);
      ahi[kk][j] = (short)hb;
      alo[kk][j] = (short)lb;
    }
  }

  #pragma unroll
  for (int ct = 0; ct < 8; ++ct) {
    f32x4 acc = {0.f, 0.f, 0.f, 0.f};
    #pragma unroll
    for (int kk = 0; kk < 4; ++kk) {
      bf16x8 b = *reinterpret_cast<const bf16x8*>(&Wt[ct * 16 + c16][kk * 32 + kg * 8]);
      acc = __builtin_amdgcn_mfma_f32_16x16x32_bf16(alo[kk], b, acc, 0, 0, 0);
      acc = __builtin_amdgcn_mfma_f32_16x16x32_bf16(ahi[kk], b, acc, 0, 0, 0);
    }
    #pragma unroll
    for (int r = 0; r < 4; ++r) {
      int gr = blockIdx.x * 64 + wv * 16 + kg * 4 + r;
      if (gr < M) h1[(size_t)gr * 128 + ct * 16 + c16] = (u16)f2bf(acc[r]);
    }
  }
}

// ---- merged scan (+dinv, +scan2 in last block): counts -> rowstart, boff ----
__global__ void scan_kernel(const u64* __restrict__ packed, int* __restrict__ rowstart,
                            int* __restrict__ bsum, int* __restrict__ boff,
                            u32* __restrict__ counter, float* __restrict__ dinvp,
                            int n, int nblk) {
  __shared__ int wsum[4];
  __shared__ bool amLast;
  int b = blockIdx.x;
  int base = b * 1024;
  int tid = threadIdx.x;
  int lane = tid & 63, wv = tid >> 6;
  int idx = base + tid * 4;
  int v0 = 0, v1 = 0, v2 = 0, v3 = 0;
  #pragma unroll
  for (int j = 0; j < 4; ++j) {
    if (idx + j < n) {
      u64 p = packed[idx + j];
      int c = (int)(p >> 48);
      if (j == 0) v0 = c; else if (j == 1) v1 = c; else if (j == 2) v2 = c; else v3 = c;
      // packed starts at 0 now; self-loop deg=1.0 added here
      float deg = 1.0f + (float)((double)(p & 0xFFFFFFFFFFFFull) * 2.3283064365386963e-10);
      dinvp[idx + j] = rsqrtf(deg);
    }
  }
  int tsum = v0 + v1 + v2 + v3;
  int inc = tsum;
  #pragma unroll
  for (int off = 1; off < 64; off <<= 1) {
    int u = __shfl_up(inc, off, 64);
    if (lane >= off) inc += u;
  }
  if (lane == 63) wsum[wv] = inc;
  __syncthreads();
  int woff = 0;
  for (int w2 = 0; w2 < wv; ++w2) woff += wsum[w2];
  int texc = woff + inc - tsum;
  if (idx     < n) rowstart[idx]     = texc;
  if (idx + 1 < n) rowstart[idx + 1] = texc + v0;
  if (idx + 2 < n) rowstart[idx + 2] = texc + v0 + v1;
  if (idx + 3 < n) rowstart[idx + 3] = texc + v0 + v1 + v2;
  if (tid == 255) {
    bsum[b] = woff + inc;
    if (b == nblk - 1) rowstart[n] = woff + inc;  // + boff[nblk-1] by consumers
  }
  // ---- last arriving block computes boff (exclusive scan of bsum) ----
  __threadfence();
  if (tid == 0) amLast = (atomicAdd(counter, 1u) == (u32)(nblk - 1));
  __syncthreads();
  if (amLast) {
    __threadfence();  // acquire: see all blocks' bsum
    int v = (tid < nblk) ? bsum[tid] : 0;
    int inc2 = v;
    #pragma unroll
    for (int off = 1; off < 64; off <<= 1) {
      int u = __shfl_up(inc2, off, 64);
      if (lane >= off) inc2 += u;
    }
    if (lane == 63) wsum[wv] = inc2;
    __syncthreads();
    int woff2 = 0;
    for (int w2 = 0; w2 < wv; ++w2) woff2 += wsum[w2];
    if (tid < nblk) boff[tid] = woff2 + inc2 - v;
  }
}

// ---- fill: erec[rowstart[d]+boff[d>>10]+rank] = (src, norm) -- no atomics ----
__global__ void fill_kernel(const int* __restrict__ src, const int* __restrict__ dst,
                            const float* __restrict__ w, const u16* __restrict__ rank,
                            const float* __restrict__ dinv, const int* __restrict__ rowstart,
                            const int* __restrict__ boff, int2* __restrict__ erec, int E) {
  int e = blockIdx.x * 256 + threadIdx.x;
  if (e < E) {
    int s = src[e], d = dst[e];
    int pos = rowstart[d] + boff[d >> 10] + (int)rank[e];
    float nrm = dinv[s] * w[e] * dinv[d];
    erec[pos] = make_int2(s, __float_as_int(nrm));
  }
}

// ---- gemm2 (MFMA): h2[M,64](bf16) = a1[M,128](bf16) @ W2[128,64] ----
__global__ __launch_bounds__(256) void gemm2_kernel(const u16* __restrict__ A,
                                                    const float* __restrict__ W2,
                                                    u16* __restrict__ C, int M) {
  __shared__ u16 Wt[64][136];
  const int tid = threadIdx.x;
  for (int i = tid; i < 128 * 64; i += 256) {
    int c = i >> 7, k = i & 127;
    Wt[c][k] = (u16)f2bf(W2[(size_t)k * 64 + c]);
  }
  __syncthreads();

  const int wv = tid >> 6;
  const int l = tid & 63;
  const int c16 = l & 15;
  const int kg = l >> 4;
  const int arow = blockIdx.x * 64 + wv * 16 + c16;
  const bool rok = arow < M;

  bf16x8 af[4];
  #pragma unroll
  for (int kk = 0; kk < 4; ++kk) {
    if (rok) {
      af[kk] = *reinterpret_cast<const bf16x8*>(A + (size_t)arow * 128 + kk * 32 + kg * 8);
    } else {
      af[kk] = bf16x8{0, 0, 0, 0, 0, 0, 0, 0};
    }
  }

  #pragma unroll
  for (int ct = 0; ct < 4; ++ct) {
    f32x4 acc = {0.f, 0.f, 0.f, 0.f};
    #pragma unroll
    for (int kk = 0; kk < 4; ++kk) {
      bf16x8 b = *reinterpret_cast<const bf16x8*>(&Wt[ct * 16 + c16][kk * 32 + kg * 8]);
      acc = __builtin_amdgcn_mfma_f32_16x16x32_bf16(af[kk], b, acc, 0, 0, 0);
    }
    #pragma unroll
    for (int r = 0; r < 4; ++r) {
      int gr = blockIdx.x * 64 + wv * 16 + kg * 4 + r;
      if (gr < M) C[(size_t)gr * 64 + ct * 16 + c16] = (u16)f2bf(acc[r]);
    }
  }
}

// ---- agg layer 1: 2 nodes/wave, 32 lanes x uint2 (256B row), 8-deep ----
__global__ __launch_bounds__(256) void agg128_relu_kernel(
    const uint2* __restrict__ H2, const int* __restrict__ rowstart,
    const int* __restrict__ boff, const int2* __restrict__ erec,
    const float* __restrict__ dinv, const float* __restrict__ bias,
    uint2* __restrict__ out2, int n) {
  int wid = (blockIdx.x * 256 + threadIdx.x) >> 6;
  int lane = threadIdx.x & 63;
  int node = wid * 2 + (lane >> 5);
  int hl = lane & 31;
  if (node >= n) return;
  float dv = dinv[node];
  float ns = dv * dv;
  uint2 hv = H2[(size_t)node * 32 + hl];
  float a0 = ns * bflo(hv.x), a1 = ns * bfhi(hv.x);
  float a2 = ns * bflo(hv.y), a3 = ns * bfhi(hv.y);
  int e  = rowstart[node] + boff[node >> 10];
  int e1 = rowstart[node + 1] + boff[(node + 1) >> 10];
  for (; e + 7 < e1; e += 8) {
    int2 r0 = erec[e], r1 = erec[e + 1], r2 = erec[e + 2], r3 = erec[e + 3];
    int2 r4 = erec[e + 4], r5 = erec[e + 5], r6 = erec[e + 6], r7 = erec[e + 7];
    uint2 v0 = H2[(size_t)r0.x * 32 + hl];
    uint2 v1 = H2[(size_t)r1.x * 32 + hl];
    uint2 v2 = H2[(size_t)r2.x * 32 + hl];
    uint2 v3 = H2[(size_t)r3.x * 32 + hl];
    uint2 v4 = H2[(size_t)r4.x * 32 + hl];
    uint2 v5 = H2[(size_t)r5.x * 32 + hl];
    uint2 v6 = H2[(size_t)r6.x * 32 + hl];
    uint2 v7 = H2[(size_t)r7.x * 32 + hl];
    float w0 = __int_as_float(r0.y), w1 = __int_as_float(r1.y);
    float w2 = __int_as_float(r2.y), w3 = __int_as_float(r3.y);
    float w4 = __int_as_float(r4.y), w5 = __int_as_float(r5.y);
    float w6 = __int_as_float(r6.y), w7 = __int_as_float(r7.y);
    a0 += w0 * bflo(v0.x) + w1 * bflo(v1.x) + w2 * bflo(v2.x) + w3 * bflo(v3.x)
        + w4 * bflo(v4.x) + w5 * bflo(v5.x) + w6 * bflo(v6.x) + w7 * bflo(v7.x);
    a1 += w0 * bfhi(v0.x) + w1 * bfhi(v1.x) + w2 * bfhi(v2.x) + w3 * bfhi(v3.x)
        + w4 * bfhi(v4.x) + w5 * bfhi(v5.x) + w6 * bfhi(v6.x) + w7 * bfhi(v7.x);
    a2 += w0 * bflo(v0.y) + w1 * bflo(v1.y) + w2 * bflo(v2.y) + w3 * bflo(v3.y)
        + w4 * bflo(v4.y) + w5 * bflo(v5.y) + w6 * bflo(v6.y) + w7 * bflo(v7.y);
    a3 += w0 * bfhi(v0.y) + w1 * bfhi(v1.y) + w2 * bfhi(v2.y) + w3 * bfhi(v3.y)
        + w4 * bfhi(v4.y) + w5 * bfhi(v5.y) + w6 * bfhi(v6.y) + w7 * bfhi(v7.y);
  }
  for (; e + 3 < e1; e += 4) {
    int2 r0 = erec[e], r1 = erec[e + 1], r2 = erec[e + 2], r3 = erec[e + 3];
    uint2 v0 = H2[(size_t)r0.x * 32 + hl];
    uint2 v1 = H2[(size_t)r1.x * 32 + hl];
    uint2 v2 = H2[(size_t)r2.x * 32 + hl];
    uint2 v3 = H2[(size_t)r3.x * 32 + hl];
    float w0 = __int_as_float(r0.y), w1 = __int_as_float(r1.y);
    float w2 = __int_as_float(r2.y), w3 = __int_as_float(r3.y);
    a0 += w0 * bflo(v0.x) + w1 * bflo(v1.x) + w2 * bflo(v2.x) + w3 * bflo(v3.x);
    a1 += w0 * bfhi(v0.x) + w1 * bfhi(v1.x) + w2 * bfhi(v2.x) + w3 * bfhi(v3.x);
    a2 += w0 * bflo(v0.y) + w1 * bflo(v1.y) + w2 * bflo(v2.y) + w3 * bflo(v3.y);
    a3 += w0 * bfhi(v0.y) + w1 * bfhi(v1.y) + w2 * bfhi(v2.y) + w3 * bfhi(v3.y);
  }
  for (; e < e1; ++e) {
    int2 r = erec[e];
    uint2 v = H2[(size_t)r.x * 32 + hl];
    float w = __int_as_float(r.y);
    a0 += w * bflo(v.x); a1 += w * bfhi(v.x);
    a2 += w * bflo(v.y); a3 += w * bfhi(v.y);
  }
  float4 bb = reinterpret_cast<const float4*>(bias)[hl];
  a0 = fmaxf(a0 + bb.x, 0.f);
  a1 = fmaxf(a1 + bb.y, 0.f);
  a2 = fmaxf(a2 + bb.z, 0.f);
  a3 = fmaxf(a3 + bb.w, 0.f);
  out2[(size_t)node * 32 + hl] = make_uint2(pack2bf(a0, a1), pack2bf(a2, a3));
}

// ---- agg layer 2: 2 nodes/wave, 32 lanes x u32 (128B row), 8-deep ----
__global__ __launch_bounds__(256) void agg64_kernel(
    const u32* __restrict__ H, const int* __restrict__ rowstart,
    const int* __restrict__ boff, const int2* __restrict__ erec,
    const float* __restrict__ dinv, const float* __restrict__ bias,
    float2* __restrict__ out2, int n) {
  int wid = (blockIdx.x * 256 + threadIdx.x) >> 6;
  int lane = threadIdx.x & 63;
  int node = wid * 2 + (lane >> 5);
  int hl = lane & 31;
  if (node >= n) return;
  float dv = dinv[node];
  float ns = dv * dv;
  u32 hv = H[(size_t)node * 32 + hl];
  float a0 = ns * bflo(hv), a1 = ns * bfhi(hv);
  int e  = rowstart[node] + boff[node >> 10];
  int e1 = rowstart[node + 1] + boff[(node + 1) >> 10];
  for (; e + 7 < e1; e += 8) {
    int2 r0 = erec[e], r1 = erec[e + 1], r2 = erec[e + 2], r3 = erec[e + 3];
    int2 r4 = erec[e + 4], r5 = erec[e + 5], r6 = erec[e + 6], r7 = erec[e + 7];
    u32 v0 = H[(size_t)r0.x * 32 + hl];
    u32 v1 = H[(size_t)r1.x * 32 + hl];
    u32 v2 = H[(size_t)r2.x * 32 + hl];
    u32 v3 = H[(size_t)r3.x * 32 + hl];
    u32 v4 = H[(size_t)r4.x * 32 + hl];
    u32 v5 = H[(size_t)r5.x * 32 + hl];
    u32 v6 = H[(size_t)r6.x * 32 + hl];
    u32 v7 = H[(size_t)r7.x * 32 + hl];
    a0 += __int_as_float(r0.y) * bflo(v0) + __int_as_float(r1.y) * bflo(v1)
        + __int_as_float(r2.y) * bflo(v2) + __int_as_float(r3.y) * bflo(v3)
        + __int_as_float(r4.y) * bflo(v4) + __int_as_float(r5.y) * bflo(v5)
        + __int_as_float(r6.y) * bflo(v6) + __int_as_float(r7.y) * bflo(v7);
    a1 += __int_as_float(r0.y) * bfhi(v0) + __int_as_float(r1.y) * bfhi(v1)
        + __int_as_float(r2.y) * bfhi(v2) + __int_as_float(r3.y) * bfhi(v3)
        + __int_as_float(r4.y) * bfhi(v4) + __int_as_float(r5.y) * bfhi(v5)
        + __int_as_float(r6.y) * bfhi(v6) + __int_as_float(r7.y) * bfhi(v7);
  }
  for (; e + 3 < e1; e += 4) {
    int2 r0 = erec[e], r1 = erec[e + 1], r2 = erec[e + 2], r3 = erec[e + 3];
    u32 v0 = H[(size_t)r0.x * 32 + hl];
    u32 v1 = H[(size_t)r1.x * 32 + hl];
    u32 v2 = H[(size_t)r2.x * 32 + hl];
    u32 v3 = H[(size_t)r3.x * 32 + hl];
    a0 += __int_as_float(r0.y) * bflo(v0) + __int_as_float(r1.y) * bflo(v1)
        + __int_as_float(r2.y) * bflo(v2) + __int_as_float(r3.y) * bflo(v3);
    a1 += __int_as_float(r0.y) * bfhi(v0) + __int_as_float(r1.y) * bfhi(v1)
        + __int_as_float(r2.y) * bfhi(v2) + __int_as_float(r3.y) * bfhi(v3);
  }
  for (; e < e1; ++e) {
    int2 r = erec[e];
    u32 v = H[(size_t)r.x * 32 + hl];
    float w = __int_as_float(r.y);
    a0 += w * bflo(v);
    a1 += w * bfhi(v);
  }
  float2 bb = reinterpret_cast<const float2*>(bias)[hl];
  out2[(size_t)node * 32 + hl] = make_float2(a0 + bb.x, a1 + bb.y);
}

extern "C" void kernel_launch(void* const* d_in, const int* in_sizes, int n_in,
                              void* d_out, int out_size, void* d_ws, size_t ws_size,
                              hipStream_t stream) {
  const float* x  = (const float*)d_in[0];
  const int*   ei = (const int*)d_in[1];
  const float* ew = (const float*)d_in[2];
  const float* W1 = (const float*)d_in[3];
  const float* b1 = (const float*)d_in[4];
  const float* W2 = (const float*)d_in[5];
  const float* b2 = (const float*)d_in[6];
  float* out = (float*)d_out;
  const int N = in_sizes[0] / 128;
  const int E = in_sizes[2];
  const int* src = ei;
  const int* dst = ei + E;

  char* wsB = (char*)d_ws;
  size_t off = 0;
  auto alloc = [&](size_t bytes) {
    void* p = wsB + off;
    off += ((bytes + 255) / 256) * 256;
    return p;
  };
  u64*   packed  = (u64*)alloc((size_t)N * 8);   // zeroed by memset below
  u32*   counter = (u32*)alloc(256);             // zeroed by same memset
  float* dinv    = (float*)alloc((size_t)N * 4);
  u16*   rank    = (u16*)alloc((size_t)E * 2);
  int*   rowst   = (int*)alloc((size_t)(N + 1) * 4);
  int*   bsum    = (int*)alloc(256 * 4);
  int*   boff    = (int*)alloc(256 * 4);
  int2*  erec    = (int2*)alloc((size_t)E * 8);
  u16*   h1      = (u16*)alloc((size_t)N * 128 * 2);  // bf16
  u16*   a1      = (u16*)alloc((size_t)N * 128 * 2);  // bf16
  u16*   h2      = h1;  // h1 dead after agg1; reuse

  const int eb = (E + 255) / 256;
  const int nbx = (N + 63) / 64;
  const int nblk = (N + 1023) / 1024;  // 98 <= 256

  // zero packed + counter in one async memset (graph-capture safe)
  hipMemsetAsync(d_ws, 0, (size_t)N * 8 + 256, stream);
  degrank_kernel<<<eb, 256, 0, stream>>>(dst, ew, packed, rank, E);
  gemm1_kernel<<<nbx, 256, 0, stream>>>(x, W1, h1, N);
  scan_kernel<<<nblk, 256, 0, stream>>>(packed, rowst, bsum, boff, counter, dinv, N, nblk);
  fill_kernel<<<eb, 256, 0, stream>>>(src, dst, ew, rank, dinv, rowst, boff, erec, E);

  const int ab = (N + 7) / 8;  // 2 nodes/wave, 8 nodes/block
  agg128_relu_kernel<<<ab, 256, 0, stream>>>((const uint2*)h1, rowst, boff, erec, dinv, b1,
                                             (uint2*)a1, N);
  gemm2_kernel<<<nbx, 256, 0, stream>>>(a1, W2, h2, N);
  agg64_kernel<<<ab, 256, 0, stream>>>((const u32*)h2, rowst, boff, erec, dinv, b2,
                                       (float2*)out, N);
}

// Round 14
// 431.652 us; speedup vs baseline: 1.0071x; 1.0071x over previous
//
#include <hip/hip_runtime.h>
#include <cstdint>
#include <cstddef>

// ---------------------------------------------------------------------------
// 2-layer GCN, bf16 intermediates. R14:
//  - erec packed to 4B/edge: src:17b | norm:15b fixed-point (norm<1 strict)
//  - agg128+gemm2 FUSED: block aggregates its 64 nodes into LDS tile, then
//    does the 64x64 MFMA gemm2 tile from LDS (a1 never hits HBM).
//    h2 is a SEPARATE buffer now (h1 still live during fused kernel).
//  - degrank: structural ~76us (21G returning-atomics/s global engine rate)
//  - gemm1: bf16 MFMA split-A (fp32 exactness); scan: merged w/ last-block
// ---------------------------------------------------------------------------

typedef unsigned long long u64;
typedef unsigned int u32;
typedef unsigned short u16;
typedef __attribute__((ext_vector_type(8))) short bf16x8;
typedef __attribute__((ext_vector_type(4))) float f32x4;

__device__ __forceinline__ float bflo(u32 u) { return __uint_as_float(u << 16); }
__device__ __forceinline__ float bfhi(u32 u) { return __uint_as_float(u & 0xffff0000u); }
__device__ __forceinline__ u32 f2bf(float f) {
  u32 u = __float_as_uint(f);
  return (u + 0x7fffu + ((u >> 16) & 1u)) >> 16;
}
__device__ __forceinline__ u32 pack2bf(float lo, float hi) {
  return f2bf(lo) | (f2bf(hi) << 16);
}
__device__ __forceinline__ float dec_norm(u32 rec) {
  return (float)(rec & 32767u) * 3.0517578125e-05f;  // /32768
}

__global__ void degrank_kernel(const int* __restrict__ dst, const float* __restrict__ w,
                               u64* packed, u16* __restrict__ rank, int E) {
  int e = blockIdx.x * 256 + threadIdx.x;
  if (e < E) {
    int d = dst[e];
    u64 add = (1ull << 48) | (u64)(w[e] * 4294967296.0f);
    u64 old = atomicAdd(&packed[d], add);
    rank[e] = (u16)(old >> 48);
  }
}

// ---- gemm1 (MFMA): h1[M,128](bf16) = x[M,128](fp32, split-A) @ W1[128,128] ----
__global__ __launch_bounds__(256) void gemm1_kernel(const float* __restrict__ x,
                                                    const float* __restrict__ W1,
                                                    u16* __restrict__ h1, int M) {
  __shared__ u16 Wt[128][136];
  const int tid = threadIdx.x;
  for (int i = tid; i < 128 * 128; i += 256) {
    int c = i >> 7, k = i & 127;
    Wt[c][k] = (u16)f2bf(W1[(size_t)k * 128 + c]);
  }
  __syncthreads();

  const int wv = tid >> 6;
  const int l = tid & 63;
  const int c16 = l & 15;
  const int kg = l >> 4;
  const int arow = blockIdx.x * 64 + wv * 16 + c16;
  const bool rok = arow < M;

  bf16x8 ahi[4], alo[4];
  #pragma unroll
  for (int kk = 0; kk < 4; ++kk) {
    float v[8];
    if (rok) {
      float4 p0 = *reinterpret_cast<const float4*>(x + (size_t)arow * 128 + kk * 32 + kg * 8);
      float4 p1 = *reinterpret_cast<const float4*>(x + (size_t)arow * 128 + kk * 32 + kg * 8 + 4);
      v[0] = p0.x; v[1] = p0.y; v[2] = p0.z; v[3] = p0.w;
      v[4] = p1.x; v[5] = p1.y; v[6] = p1.z; v[7] = p1.w;
    } else {
      #pragma unroll
      for (int j = 0; j < 8; ++j) v[j] = 0.f;
    }
    #pragma unroll
    for (int j = 0; j < 8; ++j) {
      u32 hb = f2bf(v[j]);
      float hf = __uint_as_float(hb << 16);
      u32 lb = f2bf(v[j] - hf);
      ahi[kk][j] = (short)hb;
      alo[kk][j] = (short)lb;
    }
  }

  #pragma unroll
  for (int ct = 0; ct < 8; ++ct) {
    f32x4 acc = {0.f, 0.f, 0.f, 0.f};
    #pragma unroll
    for (int kk = 0; kk < 4; ++kk) {
      bf16x8 b = *reinterpret_cast<const bf16x8*>(&Wt[ct * 16 + c16][kk * 32 + kg * 8]);
      acc = __builtin_amdgcn_mfma_f32_16x16x32_bf16(alo[kk], b, acc, 0, 0, 0);
      acc = __builtin_amdgcn_mfma_f32_16x16x32_bf16(ahi[kk], b, acc, 0, 0, 0);
    }
    #pragma unroll
    for (int r = 0; r < 4; ++r) {
      int gr = blockIdx.x * 64 + wv * 16 + kg * 4 + r;
      if (gr < M) h1[(size_t)gr * 128 + ct * 16 + c16] = (u16)f2bf(acc[r]);
    }
  }
}

// ---- merged scan (+dinv, +scan2 in last block) ----
__global__ void scan_kernel(const u64* __restrict__ packed, int* __restrict__ rowstart,
                            int* __restrict__ bsum, int* __restrict__ boff,
                            u32* __restrict__ counter, float* __restrict__ dinvp,
                            int n, int nblk) {
  __shared__ int wsum[4];
  __shared__ bool amLast;
  int b = blockIdx.x;
  int base = b * 1024;
  int tid = threadIdx.x;
  int lane = tid & 63, wv = tid >> 6;
  int idx = base + tid * 4;
  int v0 = 0, v1 = 0, v2 = 0, v3 = 0;
  #pragma unroll
  for (int j = 0; j < 4; ++j) {
    if (idx + j < n) {
      u64 p = packed[idx + j];
      int c = (int)(p >> 48);
      if (j == 0) v0 = c; else if (j == 1) v1 = c; else if (j == 2) v2 = c; else v3 = c;
      float deg = 1.0f + (float)((double)(p & 0xFFFFFFFFFFFFull) * 2.3283064365386963e-10);
      dinvp[idx + j] = rsqrtf(deg);
    }
  }
  int tsum = v0 + v1 + v2 + v3;
  int inc = tsum;
  #pragma unroll
  for (int off = 1; off < 64; off <<= 1) {
    int u = __shfl_up(inc, off, 64);
    if (lane >= off) inc += u;
  }
  if (lane == 63) wsum[wv] = inc;
  __syncthreads();
  int woff = 0;
  for (int w2 = 0; w2 < wv; ++w2) woff += wsum[w2];
  int texc = woff + inc - tsum;
  if (idx     < n) rowstart[idx]     = texc;
  if (idx + 1 < n) rowstart[idx + 1] = texc + v0;
  if (idx + 2 < n) rowstart[idx + 2] = texc + v0 + v1;
  if (idx + 3 < n) rowstart[idx + 3] = texc + v0 + v1 + v2;
  if (tid == 255) {
    bsum[b] = woff + inc;
    if (b == nblk - 1) rowstart[n] = woff + inc;
  }
  __threadfence();
  if (tid == 0) amLast = (atomicAdd(counter, 1u) == (u32)(nblk - 1));
  __syncthreads();
  if (amLast) {
    __threadfence();
    int v = (tid < nblk) ? bsum[tid] : 0;
    int inc2 = v;
    #pragma unroll
    for (int off = 1; off < 64; off <<= 1) {
      int u = __shfl_up(inc2, off, 64);
      if (lane >= off) inc2 += u;
    }
    if (lane == 63) wsum[wv] = inc2;
    __syncthreads();
    int woff2 = 0;
    for (int w2 = 0; w2 < wv; ++w2) woff2 += wsum[w2];
    if (tid < nblk) boff[tid] = woff2 + inc2 - v;
  }
}

// ---- fill: erec4[pos] = src<<15 | norm_q15 -- no atomics, 4B/edge ----
__global__ void fill_kernel(const int* __restrict__ src, const int* __restrict__ dst,
                            const float* __restrict__ w, const u16* __restrict__ rank,
                            const float* __restrict__ dinv, const int* __restrict__ rowstart,
                            const int* __restrict__ boff, u32* __restrict__ erec, int E) {
  int e = blockIdx.x * 256 + threadIdx.x;
  if (e < E) {
    int s = src[e], d = dst[e];
    int pos = rowstart[d] + boff[d >> 10] + (int)rank[e];
    float nrm = dinv[s] * w[e] * dinv[d];      // < 1 strictly
    u32 q = (u32)(nrm * 32768.0f);
    if (q > 32767u) q = 32767u;
    erec[pos] = ((u32)s << 15) | q;
  }
}

// ---- FUSED agg-layer1 + gemm2: block owns 64 nodes ----
// Phase 1: aggregate h1 rows (CSR gather) -> LDS a1 tile (relu+bias, bf16)
// Phase 2: 64x64 gemm2 tile from LDS -> h2 (global, bf16)
__global__ __launch_bounds__(512) void agg1_gemm2_kernel(
    const uint2* __restrict__ H2, const int* __restrict__ rowstart,
    const int* __restrict__ boff, const u32* __restrict__ erec,
    const float* __restrict__ dinv, const float* __restrict__ b1,
    const float* __restrict__ W2, u16* __restrict__ h2, int n) {
  __shared__ u16 A1[64][136];  // a1 tile, +8 pad (16B-aligned rows, 2-way banks)
  __shared__ u16 Wt[64][136];  // W2^T [col][k]
  const int tid = threadIdx.x;
  const int wave = tid >> 6;   // 0..7
  const int lane = tid & 63;
  const int base = blockIdx.x * 64;

  // stage W2 transposed (bf16)
  for (int i = tid; i < 64 * 128; i += 512) {
    int c = i >> 7, k = i & 127;
    Wt[c][k] = (u16)f2bf(W2[(size_t)k * 64 + c]);
  }

  // ---- phase 1: aggregate 8 nodes per wave (4 pairs; 2 nodes per wave-half) ----
  const int hl = lane & 31;
  #pragma unroll
  for (int p = 0; p < 4; ++p) {
    int r = wave * 8 + p * 2 + (lane >> 5);  // 0..63
    int node = base + r;
    if (node < n) {
      float dv = dinv[node];
      float ns = dv * dv;
      uint2 hv = H2[(size_t)node * 32 + hl];
      float a0 = ns * bflo(hv.x), a1v = ns * bfhi(hv.x);
      float a2 = ns * bflo(hv.y), a3 = ns * bfhi(hv.y);
      int e  = rowstart[node] + boff[node >> 10];
      int e1 = rowstart[node + 1] + boff[(node + 1) >> 10];
      for (; e + 3 < e1; e += 4) {
        u32 r0 = erec[e], r1 = erec[e + 1], r2 = erec[e + 2], r3 = erec[e + 3];
        uint2 v0 = H2[(size_t)(r0 >> 15) * 32 + hl];
        uint2 v1 = H2[(size_t)(r1 >> 15) * 32 + hl];
        uint2 v2 = H2[(size_t)(r2 >> 15) * 32 + hl];
        uint2 v3 = H2[(size_t)(r3 >> 15) * 32 + hl];
        float w0 = dec_norm(r0), w1 = dec_norm(r1), w2 = dec_norm(r2), w3 = dec_norm(r3);
        a0  += w0 * bflo(v0.x) + w1 * bflo(v1.x) + w2 * bflo(v2.x) + w3 * bflo(v3.x);
        a1v += w0 * bfhi(v0.x) + w1 * bfhi(v1.x) + w2 * bfhi(v2.x) + w3 * bfhi(v3.x);
        a2  += w0 * bflo(v0.y) + w1 * bflo(v1.y) + w2 * bflo(v2.y) + w3 * bflo(v3.y);
        a3  += w0 * bfhi(v0.y) + w1 * bfhi(v1.y) + w2 * bfhi(v2.y) + w3 * bfhi(v3.y);
      }
      for (; e < e1; ++e) {
        u32 rr = erec[e];
        uint2 v = H2[(size_t)(rr >> 15) * 32 + hl];
        float w = dec_norm(rr);
        a0 += w * bflo(v.x); a1v += w * bfhi(v.x);
        a2 += w * bflo(v.y); a3  += w * bfhi(v.y);
      }
      float4 bb = reinterpret_cast<const float4*>(b1)[hl];
      a0  = fmaxf(a0 + bb.x, 0.f);
      a1v = fmaxf(a1v + bb.y, 0.f);
      a2  = fmaxf(a2 + bb.z, 0.f);
      a3  = fmaxf(a3 + bb.w, 0.f);
      *reinterpret_cast<uint2*>(&A1[r][hl * 4]) =
          make_uint2(pack2bf(a0, a1v), pack2bf(a2, a3));
    } else {
      *reinterpret_cast<uint2*>(&A1[r][hl * 4]) = make_uint2(0u, 0u);
    }
  }
  __syncthreads();

  // ---- phase 2: gemm2 tile 64x64 from LDS; wave does 2 (16x16) tiles ----
  const int c16 = lane & 15;
  const int kg = lane >> 4;
  #pragma unroll
  for (int t = wave * 2; t < wave * 2 + 2; ++t) {
    int rt = t >> 2;       // row-tile 0..3
    int ctile = t & 3;     // col-tile 0..3
    f32x4 acc = {0.f, 0.f, 0.f, 0.f};
    #pragma unroll
    for (int kk = 0; kk < 4; ++kk) {
      bf16x8 a = *reinterpret_cast<const bf16x8*>(&A1[rt * 16 + c16][kk * 32 + kg * 8]);
      bf16x8 b = *reinterpret_cast<const bf16x8*>(&Wt[ctile * 16 + c16][kk * 32 + kg * 8]);
      acc = __builtin_amdgcn_mfma_f32_16x16x32_bf16(a, b, acc, 0, 0, 0);
    }
    #pragma unroll
    for (int r = 0; r < 4; ++r) {
      int grow = base + rt * 16 + kg * 4 + r;
      if (grow < n) h2[(size_t)grow * 64 + ctile * 16 + c16] = (u16)f2bf(acc[r]);
    }
  }
}

// ---- agg layer 2: 2 nodes/wave, 32 lanes x u32 (128B row), 4-deep ----
__global__ __launch_bounds__(256) void agg64_kernel(
    const u32* __restrict__ H, const int* __restrict__ rowstart,
    const int* __restrict__ boff, const u32* __restrict__ erec,
    const float* __restrict__ dinv, const float* __restrict__ bias,
    float2* __restrict__ out2, int n) {
  int wid = (blockIdx.x * 256 + threadIdx.x) >> 6;
  int lane = threadIdx.x & 63;
  int node = wid * 2 + (lane >> 5);
  int hl = lane & 31;
  if (node >= n) return;
  float dv = dinv[node];
  float ns = dv * dv;
  u32 hv = H[(size_t)node * 32 + hl];
  float a0 = ns * bflo(hv), a1 = ns * bfhi(hv);
  int e  = rowstart[node] + boff[node >> 10];
  int e1 = rowstart[node + 1] + boff[(node + 1) >> 10];
  for (; e + 3 < e1; e += 4) {
    u32 r0 = erec[e], r1 = erec[e + 1], r2 = erec[e + 2], r3 = erec[e + 3];
    u32 v0 = H[(size_t)(r0 >> 15) * 32 + hl];
    u32 v1 = H[(size_t)(r1 >> 15) * 32 + hl];
    u32 v2 = H[(size_t)(r2 >> 15) * 32 + hl];
    u32 v3 = H[(size_t)(r3 >> 15) * 32 + hl];
    float w0 = dec_norm(r0), w1 = dec_norm(r1), w2 = dec_norm(r2), w3 = dec_norm(r3);
    a0 += w0 * bflo(v0) + w1 * bflo(v1) + w2 * bflo(v2) + w3 * bflo(v3);
    a1 += w0 * bfhi(v0) + w1 * bfhi(v1) + w2 * bfhi(v2) + w3 * bfhi(v3);
  }
  for (; e < e1; ++e) {
    u32 rr = erec[e];
    u32 v = H[(size_t)(rr >> 15) * 32 + hl];
    float w = dec_norm(rr);
    a0 += w * bflo(v);
    a1 += w * bfhi(v);
  }
  float2 bb = reinterpret_cast<const float2*>(bias)[hl];
  out2[(size_t)node * 32 + hl] = make_float2(a0 + bb.x, a1 + bb.y);
}

extern "C" void kernel_launch(void* const* d_in, const int* in_sizes, int n_in,
                              void* d_out, int out_size, void* d_ws, size_t ws_size,
                              hipStream_t stream) {
  const float* x  = (const float*)d_in[0];
  const int*   ei = (const int*)d_in[1];
  const float* ew = (const float*)d_in[2];
  const float* W1 = (const float*)d_in[3];
  const float* b1 = (const float*)d_in[4];
  const float* W2 = (const float*)d_in[5];
  const float* b2 = (const float*)d_in[6];
  float* out = (float*)d_out;
  const int N = in_sizes[0] / 128;
  const int E = in_sizes[2];
  const int* src = ei;
  const int* dst = ei + E;

  char* wsB = (char*)d_ws;
  size_t off = 0;
  auto alloc = [&](size_t bytes) {
    void* p = wsB + off;
    off += ((bytes + 255) / 256) * 256;
    return p;
  };
  u64*   packed  = (u64*)alloc((size_t)N * 8);   // zeroed by memset below
  u32*   counter = (u32*)alloc(256);             // zeroed by same memset
  float* dinv    = (float*)alloc((size_t)N * 4);
  u16*   rank    = (u16*)alloc((size_t)E * 2);
  int*   rowst   = (int*)alloc((size_t)(N + 1) * 4);
  int*   bsum    = (int*)alloc(256 * 4);
  int*   boff    = (int*)alloc(256 * 4);
  u32*   erec    = (u32*)alloc((size_t)E * 4);   // 4B/edge
  u16*   h1      = (u16*)alloc((size_t)N * 128 * 2);  // bf16
  u16*   h2      = (u16*)alloc((size_t)N * 64 * 2);   // bf16 (NOT aliased: h1 live)

  const int eb = (E + 255) / 256;
  const int nbx = (N + 63) / 64;
  const int nblk = (N + 1023) / 1024;  // 98 <= 256

  hipMemsetAsync(d_ws, 0, (size_t)N * 8 + 256, stream);
  degrank_kernel<<<eb, 256, 0, stream>>>(dst, ew, packed, rank, E);
  gemm1_kernel<<<nbx, 256, 0, stream>>>(x, W1, h1, N);
  scan_kernel<<<nblk, 256, 0, stream>>>(packed, rowst, bsum, boff, counter, dinv, N, nblk);
  fill_kernel<<<eb, 256, 0, stream>>>(src, dst, ew, rank, dinv, rowst, boff, erec, E);

  agg1_gemm2_kernel<<<nbx, 512, 0, stream>>>((const uint2*)h1, rowst, boff, erec, dinv,
                                             b1, W2, h2, N);
  const int ab = (N + 7) / 8;
  agg64_kernel<<<ab, 256, 0, stream>>>((const u32*)h2, rowst, boff, erec, dinv, b2,
                                       (float2*)out, N);
}

// Round 15
// 418.529 us; speedup vs baseline: 1.0387x; 1.0314x over previous
//
#include <hip/hip_runtime.h>
#include <cstdint>
#include <cstddef>

// ---------------------------------------------------------------------------
// 2-layer GCN, bf16 intermediates. R15: dinv FOLDED into features.
//   h1' = dinv (.) (x@W1)   [gemm1 epilogue, coalesced dinv read]
//   h2' = dinv (.) (a1@W2)  [fused-kernel epilogue]
//   agg(d) = dinv[d] * ( sum_e w_e * h'[src_e] + h'[d] )   (+bias, relu)
//   => erec = (src:17b | w:q15) -- fill has NO random gathers at all.
// Pipeline: memset -> degrank -> scan(dinv) -> gemm1' -> fill -> fused
//   agg1+gemm2 -> agg64. Single stream (serial), so reorder costs nothing.
// degrank: ~76us structural (21G returning-atomics/s engine rate).
// ---------------------------------------------------------------------------

typedef unsigned long long u64;
typedef unsigned int u32;
typedef unsigned short u16;
typedef __attribute__((ext_vector_type(8))) short bf16x8;
typedef __attribute__((ext_vector_type(4))) float f32x4;

__device__ __forceinline__ float bflo(u32 u) { return __uint_as_float(u << 16); }
__device__ __forceinline__ float bfhi(u32 u) { return __uint_as_float(u & 0xffff0000u); }
__device__ __forceinline__ u32 f2bf(float f) {
  u32 u = __float_as_uint(f);
  return (u + 0x7fffu + ((u >> 16) & 1u)) >> 16;
}
__device__ __forceinline__ u32 pack2bf(float lo, float hi) {
  return f2bf(lo) | (f2bf(hi) << 16);
}
__device__ __forceinline__ float dec_w(u32 rec) {
  return (float)(rec & 32767u) * 3.0517578125e-05f;  // /32768
}

__global__ void degrank_kernel(const int* __restrict__ dst, const float* __restrict__ w,
                               u64* packed, u16* __restrict__ rank, int E) {
  int e = blockIdx.x * 256 + threadIdx.x;
  if (e < E) {
    int d = dst[e];
    u64 add = (1ull << 48) | (u64)(w[e] * 4294967296.0f);
    u64 old = atomicAdd(&packed[d], add);
    rank[e] = (u16)(old >> 48);
  }
}

// ---- merged scan (+dinv, +scan2 in last block) ----
__global__ void scan_kernel(const u64* __restrict__ packed, int* __restrict__ rowstart,
                            int* __restrict__ bsum, int* __restrict__ boff,
                            u32* __restrict__ counter, float* __restrict__ dinvp,
                            int n, int nblk) {
  __shared__ int wsum[4];
  __shared__ bool amLast;
  int b = blockIdx.x;
  int base = b * 1024;
  int tid = threadIdx.x;
  int lane = tid & 63, wv = tid >> 6;
  int idx = base + tid * 4;
  int v0 = 0, v1 = 0, v2 = 0, v3 = 0;
  #pragma unroll
  for (int j = 0; j < 4; ++j) {
    if (idx + j < n) {
      u64 p = packed[idx + j];
      int c = (int)(p >> 48);
      if (j == 0) v0 = c; else if (j == 1) v1 = c; else if (j == 2) v2 = c; else v3 = c;
      float deg = 1.0f + (float)((double)(p & 0xFFFFFFFFFFFFull) * 2.3283064365386963e-10);
      dinvp[idx + j] = rsqrtf(deg);
    }
  }
  int tsum = v0 + v1 + v2 + v3;
  int inc = tsum;
  #pragma unroll
  for (int off = 1; off < 64; off <<= 1) {
    int u = __shfl_up(inc, off, 64);
    if (lane >= off) inc += u;
  }
  if (lane == 63) wsum[wv] = inc;
  __syncthreads();
  int woff = 0;
  for (int w2 = 0; w2 < wv; ++w2) woff += wsum[w2];
  int texc = woff + inc - tsum;
  if (idx     < n) rowstart[idx]     = texc;
  if (idx + 1 < n) rowstart[idx + 1] = texc + v0;
  if (idx + 2 < n) rowstart[idx + 2] = texc + v0 + v1;
  if (idx + 3 < n) rowstart[idx + 3] = texc + v0 + v1 + v2;
  if (tid == 255) {
    bsum[b] = woff + inc;
    if (b == nblk - 1) rowstart[n] = woff + inc;
  }
  __threadfence();
  if (tid == 0) amLast = (atomicAdd(counter, 1u) == (u32)(nblk - 1));
  __syncthreads();
  if (amLast) {
    __threadfence();
    int v = (tid < nblk) ? bsum[tid] : 0;
    int inc2 = v;
    #pragma unroll
    for (int off = 1; off < 64; off <<= 1) {
      int u = __shfl_up(inc2, off, 64);
      if (lane >= off) inc2 += u;
    }
    if (lane == 63) wsum[wv] = inc2;
    __syncthreads();
    int woff2 = 0;
    for (int w2 = 0; w2 < wv; ++w2) woff2 += wsum[w2];
    if (tid < nblk) boff[tid] = woff2 + inc2 - v;
  }
}

// ---- gemm1 (MFMA, split-A): h1'[M,128](bf16) = dinv (.) (x @ W1) ----
__global__ __launch_bounds__(256) void gemm1_kernel(const float* __restrict__ x,
                                                    const float* __restrict__ W1,
                                                    const float* __restrict__ dinv,
                                                    u16* __restrict__ h1, int M) {
  __shared__ u16 Wt[128][136];
  const int tid = threadIdx.x;
  for (int i = tid; i < 128 * 128; i += 256) {
    int c = i >> 7, k = i & 127;
    Wt[c][k] = (u16)f2bf(W1[(size_t)k * 128 + c]);
  }
  __syncthreads();

  const int wv = tid >> 6;
  const int l = tid & 63;
  const int c16 = l & 15;
  const int kg = l >> 4;
  const int arow = blockIdx.x * 64 + wv * 16 + c16;
  const bool rok = arow < M;

  bf16x8 ahi[4], alo[4];
  #pragma unroll
  for (int kk = 0; kk < 4; ++kk) {
    float v[8];
    if (rok) {
      float4 p0 = *reinterpret_cast<const float4*>(x + (size_t)arow * 128 + kk * 32 + kg * 8);
      float4 p1 = *reinterpret_cast<const float4*>(x + (size_t)arow * 128 + kk * 32 + kg * 8 + 4);
      v[0] = p0.x; v[1] = p0.y; v[2] = p0.z; v[3] = p0.w;
      v[4] = p1.x; v[5] = p1.y; v[6] = p1.z; v[7] = p1.w;
    } else {
      #pragma unroll
      for (int j = 0; j < 8; ++j) v[j] = 0.f;
    }
    #pragma unroll
    for (int j = 0; j < 8; ++j) {
      u32 hb = f2bf(v[j]);
      float hf = __uint_as_float(hb << 16);
      u32 lb = f2bf(v[j] - hf);
      ahi[kk][j] = (short)hb;
      alo[kk][j] = (short)lb;
    }
  }

  // per-thread output rows: gr = base + wv*16 + kg*4 + r
  float dvv[4];
  #pragma unroll
  for (int r = 0; r < 4; ++r) {
    int gr = blockIdx.x * 64 + wv * 16 + kg * 4 + r;
    dvv[r] = (gr < M) ? dinv[gr] : 0.f;
  }

  #pragma unroll
  for (int ct = 0; ct < 8; ++ct) {
    f32x4 acc = {0.f, 0.f, 0.f, 0.f};
    #pragma unroll
    for (int kk = 0; kk < 4; ++kk) {
      bf16x8 b = *reinterpret_cast<const bf16x8*>(&Wt[ct * 16 + c16][kk * 32 + kg * 8]);
      acc = __builtin_amdgcn_mfma_f32_16x16x32_bf16(alo[kk], b, acc, 0, 0, 0);
      acc = __builtin_amdgcn_mfma_f32_16x16x32_bf16(ahi[kk], b, acc, 0, 0, 0);
    }
    #pragma unroll
    for (int r = 0; r < 4; ++r) {
      int gr = blockIdx.x * 64 + wv * 16 + kg * 4 + r;
      if (gr < M) h1[(size_t)gr * 128 + ct * 16 + c16] = (u16)f2bf(dvv[r] * acc[r]);
    }
  }
}

// ---- fill: erec[pos] = src<<15 | q15(w) -- sequential reads only ----
__global__ void fill_kernel(const int* __restrict__ src, const int* __restrict__ dst,
                            const float* __restrict__ w, const u16* __restrict__ rank,
                            const int* __restrict__ rowstart, const int* __restrict__ boff,
                            u32* __restrict__ erec, int E) {
  int e = blockIdx.x * 256 + threadIdx.x;
  if (e < E) {
    int d = dst[e];
    int pos = rowstart[d] + boff[d >> 10] + (int)rank[e];
    u32 q = (u32)(w[e] * 32768.0f);
    if (q > 32767u) q = 32767u;
    erec[pos] = ((u32)src[e] << 15) | q;
  }
}

// ---- FUSED agg-layer1 + gemm2 ----
// Phase 1: a1[r] = relu(dinv[r]*(sum_e w*h1'[src] + h1'[r]) + b1) -> LDS
// Phase 2: h2'[r] = dinv[r] * (a1 @ W2)  (64x64 MFMA tile from LDS)
__global__ __launch_bounds__(512) void agg1_gemm2_kernel(
    const uint2* __restrict__ H2, const int* __restrict__ rowstart,
    const int* __restrict__ boff, const u32* __restrict__ erec,
    const float* __restrict__ dinv, const float* __restrict__ b1,
    const float* __restrict__ W2, u16* __restrict__ h2, int n) {
  __shared__ u16 A1[64][136];
  __shared__ u16 Wt[64][136];
  const int tid = threadIdx.x;
  const int wave = tid >> 6;
  const int lane = tid & 63;
  const int base = blockIdx.x * 64;

  for (int i = tid; i < 64 * 128; i += 512) {
    int c = i >> 7, k = i & 127;
    Wt[c][k] = (u16)f2bf(W2[(size_t)k * 64 + c]);
  }

  const int hl = lane & 31;
  #pragma unroll
  for (int p = 0; p < 4; ++p) {
    int r = wave * 8 + p * 2 + (lane >> 5);
    int node = base + r;
    if (node < n) {
      float dv = dinv[node];
      uint2 hv = H2[(size_t)node * 32 + hl];
      float a0 = bflo(hv.x), a1v = bfhi(hv.x);
      float a2 = bflo(hv.y), a3 = bfhi(hv.y);
      int e  = rowstart[node] + boff[node >> 10];
      int e1 = rowstart[node + 1] + boff[(node + 1) >> 10];
      for (; e + 3 < e1; e += 4) {
        u32 r0 = erec[e], r1 = erec[e + 1], r2 = erec[e + 2], r3 = erec[e + 3];
        uint2 v0 = H2[(size_t)(r0 >> 15) * 32 + hl];
        uint2 v1 = H2[(size_t)(r1 >> 15) * 32 + hl];
        uint2 v2 = H2[(size_t)(r2 >> 15) * 32 + hl];
        uint2 v3 = H2[(size_t)(r3 >> 15) * 32 + hl];
        float w0 = dec_w(r0), w1 = dec_w(r1), w2 = dec_w(r2), w3 = dec_w(r3);
        a0  += w0 * bflo(v0.x) + w1 * bflo(v1.x) + w2 * bflo(v2.x) + w3 * bflo(v3.x);
        a1v += w0 * bfhi(v0.x) + w1 * bfhi(v1.x) + w2 * bfhi(v2.x) + w3 * bfhi(v3.x);
        a2  += w0 * bflo(v0.y) + w1 * bflo(v1.y) + w2 * bflo(v2.y) + w3 * bflo(v3.y);
        a3  += w0 * bfhi(v0.y) + w1 * bfhi(v1.y) + w2 * bfhi(v2.y) + w3 * bfhi(v3.y);
      }
      for (; e < e1; ++e) {
        u32 rr = erec[e];
        uint2 v = H2[(size_t)(rr >> 15) * 32 + hl];
        float w = dec_w(rr);
        a0 += w * bflo(v.x); a1v += w * bfhi(v.x);
        a2 += w * bflo(v.y); a3  += w * bfhi(v.y);
      }
      float4 bb = reinterpret_cast<const float4*>(b1)[hl];
      a0  = fmaxf(dv * a0 + bb.x, 0.f);
      a1v = fmaxf(dv * a1v + bb.y, 0.f);
      a2  = fmaxf(dv * a2 + bb.z, 0.f);
      a3  = fmaxf(dv * a3 + bb.w, 0.f);
      *reinterpret_cast<uint2*>(&A1[r][hl * 4]) =
          make_uint2(pack2bf(a0, a1v), pack2bf(a2, a3));
    } else {
      *reinterpret_cast<uint2*>(&A1[r][hl * 4]) = make_uint2(0u, 0u);
    }
  }
  __syncthreads();

  const int c16 = lane & 15;
  const int kg = lane >> 4;
  #pragma unroll
  for (int t = wave * 2; t < wave * 2 + 2; ++t) {
    int rt = t >> 2;
    int ctile = t & 3;
    f32x4 acc = {0.f, 0.f, 0.f, 0.f};
    #pragma unroll
    for (int kk = 0; kk < 4; ++kk) {
      bf16x8 a = *reinterpret_cast<const bf16x8*>(&A1[rt * 16 + c16][kk * 32 + kg * 8]);
      bf16x8 b = *reinterpret_cast<const bf16x8*>(&Wt[ctile * 16 + c16][kk * 32 + kg * 8]);
      acc = __builtin_amdgcn_mfma_f32_16x16x32_bf16(a, b, acc, 0, 0, 0);
    }
    #pragma unroll
    for (int r = 0; r < 4; ++r) {
      int grow = base + rt * 16 + kg * 4 + r;
      if (grow < n) {
        float dv2 = dinv[grow];
        h2[(size_t)grow * 64 + ctile * 16 + c16] = (u16)f2bf(dv2 * acc[r]);
      }
    }
  }
}

// ---- agg layer 2: out[d] = dinv[d]*(sum w*h2'[src] + h2'[d]) + b2 ----
__global__ __launch_bounds__(256) void agg64_kernel(
    const u32* __restrict__ H, const int* __restrict__ rowstart,
    const int* __restrict__ boff, const u32* __restrict__ erec,
    const float* __restrict__ dinv, const float* __restrict__ bias,
    float2* __restrict__ out2, int n) {
  int wid = (blockIdx.x * 256 + threadIdx.x) >> 6;
  int lane = threadIdx.x & 63;
  int node = wid * 2 + (lane >> 5);
  int hl = lane & 31;
  if (node >= n) return;
  float dv = dinv[node];
  u32 hv = H[(size_t)node * 32 + hl];
  float a0 = bflo(hv), a1 = bfhi(hv);
  int e  = rowstart[node] + boff[node >> 10];
  int e1 = rowstart[node + 1] + boff[(node + 1) >> 10];
  for (; e + 3 < e1; e += 4) {
    u32 r0 = erec[e], r1 = erec[e + 1], r2 = erec[e + 2], r3 = erec[e + 3];
    u32 v0 = H[(size_t)(r0 >> 15) * 32 + hl];
    u32 v1 = H[(size_t)(r1 >> 15) * 32 + hl];
    u32 v2 = H[(size_t)(r2 >> 15) * 32 + hl];
    u32 v3 = H[(size_t)(r3 >> 15) * 32 + hl];
    float w0 = dec_w(r0), w1 = dec_w(r1), w2 = dec_w(r2), w3 = dec_w(r3);
    a0 += w0 * bflo(v0) + w1 * bflo(v1) + w2 * bflo(v2) + w3 * bflo(v3);
    a1 += w0 * bfhi(v0) + w1 * bfhi(v1) + w2 * bfhi(v2) + w3 * bfhi(v3);
  }
  for (; e < e1; ++e) {
    u32 rr = erec[e];
    u32 v = H[(size_t)(rr >> 15) * 32 + hl];
    float w = dec_w(rr);
    a0 += w * bflo(v);
    a1 += w * bfhi(v);
  }
  float2 bb = reinterpret_cast<const float2*>(bias)[hl];
  out2[(size_t)node * 32 + hl] = make_float2(dv * a0 + bb.x, dv * a1 + bb.y);
}

extern "C" void kernel_launch(void* const* d_in, const int* in_sizes, int n_in,
                              void* d_out, int out_size, void* d_ws, size_t ws_size,
                              hipStream_t stream) {
  const float* x  = (const float*)d_in[0];
  const int*   ei = (const int*)d_in[1];
  const float* ew = (const float*)d_in[2];
  const float* W1 = (const float*)d_in[3];
  const float* b1 = (const float*)d_in[4];
  const float* W2 = (const float*)d_in[5];
  const float* b2 = (const float*)d_in[6];
  float* out = (float*)d_out;
  const int N = in_sizes[0] / 128;
  const int E = in_sizes[2];
  const int* src = ei;
  const int* dst = ei + E;

  char* wsB = (char*)d_ws;
  size_t off = 0;
  auto alloc = [&](size_t bytes) {
    void* p = wsB + off;
    off += ((bytes + 255) / 256) * 256;
    return p;
  };
  u64*   packed  = (u64*)alloc((size_t)N * 8);   // zeroed by memset below
  u32*   counter = (u32*)alloc(256);             // zeroed by same memset
  float* dinv    = (float*)alloc((size_t)N * 4);
  u16*   rank    = (u16*)alloc((size_t)E * 2);
  int*   rowst   = (int*)alloc((size_t)(N + 1) * 4);
  int*   bsum    = (int*)alloc(256 * 4);
  int*   boff    = (int*)alloc(256 * 4);
  u32*   erec    = (u32*)alloc((size_t)E * 4);
  u16*   h1      = (u16*)alloc((size_t)N * 128 * 2);  // bf16, dinv-scaled
  u16*   h2      = (u16*)alloc((size_t)N * 64 * 2);   // bf16, dinv-scaled

  const int eb = (E + 255) / 256;
  const int nbx = (N + 63) / 64;
  const int nblk = (N + 1023) / 1024;  // 98 <= 256

  hipMemsetAsync(d_ws, 0, (size_t)N * 8 + 256, stream);
  degrank_kernel<<<eb, 256, 0, stream>>>(dst, ew, packed, rank, E);
  scan_kernel<<<nblk, 256, 0, stream>>>(packed, rowst, bsum, boff, counter, dinv, N, nblk);
  gemm1_kernel<<<nbx, 256, 0, stream>>>(x, W1, dinv, h1, N);
  fill_kernel<<<eb, 256, 0, stream>>>(src, dst, ew, rank, rowst, boff, erec, E);

  agg1_gemm2_kernel<<<nbx, 512, 0, stream>>>((const uint2*)h1, rowst, boff, erec, dinv,
                                             b1, W2, h2, N);
  const int ab = (N + 7) / 8;
  agg64_kernel<<<ab, 256, 0, stream>>>((const u32*)h2, rowst, boff, erec, dinv, b2,
                                       (float2*)out, N);
}